// Round 1
// baseline (207.430 us; speedup 1.0000x reference)
//
#include <hip/hip_runtime.h>
#include <math.h>

#define M_ 48
#define L_ 48
#define N_ 256
#define NPAIR (M_*M_)        // 2304
#define THREADS 256
#define PPT (NPAIR/THREADS)  // 9 pairs per thread

// One block per sample. State per sample is the rank-1 prefix vector g[m];
// suffix products of full site matrices are fixed -> checkpointed every 8
// sites in registers (statically indexed via full unroll), <=7-site recompute.
__launch_bounds__(THREADS, 1)
__global__ void mps_sample_kernel(const float* __restrict__ inp,
                                  const float* __restrict__ theta,
                                  const float* __restrict__ coef,
                                  const float* __restrict__ rand_u,
                                  float* __restrict__ out)
{
    const int n   = blockIdx.x;
    const int tid = threadIdx.x;

    __shared__ double s_px[L_][M_];   // site-major: s_px[l][m]
    __shared__ double s_py[L_][M_];
    __shared__ double s_g[M_];
    __shared__ double s_r0[4], s_r1[4];
    __shared__ double s_init;
    __shared__ int    s_bit;

    const double PI_2 = 1.5707963267948966;

    // ---- build px/py (f64 trig) ----
    #pragma unroll
    for (int i = 0; i < PPT; ++i) {
        int j = tid + THREADS * i;           // 0..2303
        int l = j / M_, m = j - l * M_;
        double a  = (double)inp[n * L_ + l] * ((double)(m + 1) * PI_2);
        double th = (double)theta[l * M_ + m];
        double ca, sa, ct, st;
        sincos(a,  &sa, &ca);
        sincos(th, &st, &ct);
        double cf = (double)coef[m];
        s_px[l][m] = cf * (ct * ca - st * sa);   // component 0 (cos)
        s_py[l][m] = cf * (st * ca + ct * sa);   // component 1 (sin)
    }
    if (tid < M_) s_g[tid] = 1.0;
    __syncthreads();

    // pair indices (j = tid + 256*i -> consecutive lanes get consecutive k)
    int pm[PPT], pk[PPT];
    #pragma unroll
    for (int i = 0; i < PPT; ++i) {
        int j = tid + THREADS * i;
        pm[i] = j / M_;
        pk[i] = j - pm[i] * M_;
    }

    // suffix checkpoints: ckpt[s] = S_{8(s+1)} = prod_{l'>=8(s+1)} T_l',  ckpt[5]=1
    double ckpt[6][PPT];
    #pragma unroll
    for (int i = 0; i < PPT; ++i) ckpt[5][i] = 1.0;
    #pragma unroll
    for (int s = 4; s >= 0; --s) {
        #pragma unroll
        for (int i = 0; i < PPT; ++i) {
            int m = pm[i], k = pk[i];
            double C = ckpt[s + 1][i];
            #pragma unroll
            for (int lp = 0; lp < 8; ++lp) {
                int l = 8 * (s + 1) + lp;
                C *= (s_px[l][m] * s_px[l][k] + s_py[l][m] * s_py[l][k]);
            }
            ckpt[s][i] = C;
        }
    }

    // ---- sequential measurement over 48 sites ----
    #pragma unroll
    for (int seg = 0; seg < 6; ++seg) {
        for (int ls = 0; ls < 8; ++ls) {
            const int l = seg * 8 + ls;
            double n0 = 0.0, n1 = 0.0;
            #pragma unroll
            for (int i = 0; i < PPT; ++i) {
                int m = pm[i], k = pk[i];
                double C = ckpt[seg][i];                 // S_{8seg+8}
                for (int lp = seg * 8 + 7; lp > l; --lp) // recompute to S_{l+1}
                    C *= (s_px[lp][m] * s_px[lp][k] + s_py[lp][m] * s_py[lp][k]);
                double w = s_g[m] * s_g[k] * C;
                n0 += w * (s_px[l][m] * s_px[l][k]);
                n1 += w * (s_py[l][m] * s_py[l][k]);
            }
            // wave reduce (64 lanes)
            #pragma unroll
            for (int off = 32; off > 0; off >>= 1) {
                n0 += __shfl_down(n0, off, 64);
                n1 += __shfl_down(n1, off, 64);
            }
            int wv = tid >> 6;
            if ((tid & 63) == 0) { s_r0[wv] = n0; s_r1[wv] = n1; }
            __syncthreads();
            if (tid == 0) {
                double D0 = s_r0[0] + s_r0[1] + s_r0[2] + s_r0[3];
                double D1 = s_r1[0] + s_r1[1] + s_r1[2] + s_r1[3];
                double denom = fabs(D0 + D1);            // |inner(cur)|
                double p1 = fabs(D1) / denom;
                if (seg == 0 && ls == 0) s_init = denom;
                double u = (double)rand_u[l * N_ + n];
                int bit = (u < p1) ? 1 : 0;
                s_bit = bit;
                out[n * L_ + l] = (float)bit;            // measurement as 0/1 float
            }
            __syncthreads();
            int bit = s_bit;
            if (tid < M_) s_g[tid] *= bit ? s_py[l][tid] : s_px[l][tid];
            __syncthreads();
        }
    }

    if (tid == 0) {
        double sg = 0.0;
        #pragma unroll
        for (int m = 0; m < M_; ++m) sg += s_g[m];
        out[N_ * L_ + n] = (float)((sg * sg) / s_init);  // P_m
    }
}

extern "C" void kernel_launch(void* const* d_in, const int* in_sizes, int n_in,
                              void* d_out, int out_size, void* d_ws, size_t ws_size,
                              hipStream_t stream) {
    const float* inp    = (const float*)d_in[0];   // (N,L)
    const float* theta  = (const float*)d_in[1];   // (L,M)
    const float* coef   = (const float*)d_in[2];   // (M,)
    const float* rand_u = (const float*)d_in[3];   // (L,N)
    float* out = (float*)d_out;                    // N*L bits then N probs
    mps_sample_kernel<<<N_, THREADS, 0, stream>>>(inp, theta, coef, rand_u, out);
}

// Round 2
// 112.734 us; speedup vs baseline: 1.8400x; 1.8400x over previous
//
#include <hip/hip_runtime.h>
#include <math.h>

#define M_ 48
#define L_ 48
#define N_ 256
#define THREADS 256
#define NPAIR_UT 1176          // upper triangle incl. diagonal: 48*49/2
#define PPT 5                  // ceil(1176/256) pairs per thread (dummies weight 0)

// One block per sample (256 blocks = 256 CUs). Per-sample state is the rank-1
// prefix vector g[m] (per-thread register copies). Suffix site-matrices are
// fixed: checkpointed every 8 sites, expanded at segment start into per-step
// register values R[8]. Carried denominator: denom(l) = num_bit(l-1), so only
// num1 is reduced per step and P_m = denom_final/denom_init is free.
__launch_bounds__(THREADS, 1)
__global__ void mps_sample_kernel(const float* __restrict__ inp,
                                  const float* __restrict__ theta,
                                  const float* __restrict__ coef,
                                  const float* __restrict__ rand_u,
                                  float* __restrict__ out)
{
    const int n   = blockIdx.x;
    const int tid = threadIdx.x;

    __shared__ double s_px[L_][M_];   // site-major
    __shared__ double s_py[L_][M_];
    __shared__ float  s_u[L_];
    __shared__ double s_p1[2][4];     // per-wave num1 partials, dbuf by step parity
    __shared__ double s_p0[4];        // num0 partials (step 0 only)

    const double PI_2 = 1.5707963267948966;

    // ---- build px/py (f64, angle-addition: coef*cos(theta+a), coef*sin(theta+a)) ----
    #pragma unroll
    for (int i = 0; i < 9; ++i) {
        int j = tid + THREADS * i;                 // 0..2303
        int l = j / M_, m = j - l * M_;
        double a  = (double)inp[n * L_ + l] * ((double)(m + 1) * PI_2);
        double th = (double)theta[l * M_ + m];
        double sv, cv;
        sincos(th + a, &sv, &cv);
        double cf = (double)coef[m];
        s_px[l][m] = cf * cv;                      // component 0 (cos)
        s_py[l][m] = cf * sv;                      // component 1 (sin)
    }
    if (tid < L_) s_u[tid] = rand_u[tid * N_ + n]; // prefetch all random draws
    __syncthreads();

    // ---- upper-triangle pair assignment; weight folded into checkpoint seed ----
    int pm[PPT], pk[PPT];
    double ckpt[6][PPT];
    #pragma unroll
    for (int i = 0; i < PPT; ++i) {
        int p = tid + THREADS * i;
        if (p < NPAIR_UT) {
            int m = 0, r = p;
            while (r >= M_ - m) { r -= M_ - m; ++m; }
            pm[i] = m; pk[i] = m + r;
            ckpt[5][i] = (r == 0) ? 1.0 : 2.0;     // diagonal weight 1, off-diag 2
        } else { pm[i] = 0; pk[i] = 0; ckpt[5][i] = 0.0; }
    }

    // ---- suffix checkpoints: ckpt[s] = w * prod_{l'>=8(s+1)} T_l' ----
    #pragma unroll
    for (int s = 4; s >= 0; --s) {
        #pragma unroll
        for (int i = 0; i < PPT; ++i) {
            int m = pm[i], k = pk[i];
            double C = ckpt[s + 1][i];
            #pragma unroll
            for (int lp = 0; lp < 8; ++lp) {
                int l = 8 * (s + 1) + lp;
                C *= (s_px[l][m] * s_px[l][k] + s_py[l][m] * s_py[l][k]);
            }
            ckpt[s][i] = C;
        }
    }

    double gm[PPT], gk[PPT];
    #pragma unroll
    for (int i = 0; i < PPT; ++i) { gm[i] = 1.0; gk[i] = 1.0; }

    double denom = 0.0, initd = 0.0;
    double R[8][PPT];

    #pragma unroll
    for (int seg = 0; seg < 6; ++seg) {
        // segment expansion: R[j] = w * prod_{l'>=8seg+j+1} T_l'  (registers)
        #pragma unroll
        for (int i = 0; i < PPT; ++i) R[7][i] = ckpt[seg][i];
        #pragma unroll
        for (int j = 6; j >= 0; --j) {
            int l2 = 8 * seg + j + 1;
            #pragma unroll
            for (int i = 0; i < PPT; ++i) {
                int m = pm[i], k = pk[i];
                R[j][i] = R[j + 1][i] *
                    (s_px[l2][m] * s_px[l2][k] + s_py[l2][m] * s_py[l2][k]);
            }
        }

        #pragma unroll
        for (int ls = 0; ls < 8; ++ls) {
            const int l = seg * 8 + ls;
            double pxm[PPT], pxk[PPT], pym[PPT], pyk[PPT];
            double n1p = 0.0, n0p = 0.0;
            #pragma unroll
            for (int i = 0; i < PPT; ++i) {
                int m = pm[i], k = pk[i];
                pxm[i] = s_px[l][m]; pxk[i] = s_px[l][k];
                pym[i] = s_py[l][m]; pyk[i] = s_py[l][k];
                double w = gm[i] * gk[i] * R[ls][i];
                n1p += w * (pym[i] * pyk[i]);
                if (seg == 0 && ls == 0) n0p += w * (pxm[i] * pxk[i]);
            }
            // wave reduce (64 lanes)
            #pragma unroll
            for (int off = 32; off > 0; off >>= 1) {
                n1p += __shfl_down(n1p, off, 64);
                if (seg == 0 && ls == 0) n0p += __shfl_down(n0p, off, 64);
            }
            const int par = l & 1;
            if ((tid & 63) == 0) {
                s_p1[par][tid >> 6] = n1p;
                if (seg == 0 && ls == 0) s_p0[tid >> 6] = n0p;
            }
            __syncthreads();
            double n1 = s_p1[par][0] + s_p1[par][1] + s_p1[par][2] + s_p1[par][3];
            if (seg == 0 && ls == 0) {
                double n0 = s_p0[0] + s_p0[1] + s_p0[2] + s_p0[3];
                denom = fabs(n0 + n1);
                initd = denom;
            }
            double p1 = fabs(n1) / denom;          // redundant in every thread
            int bit = ((double)s_u[l] < p1) ? 1 : 0;
            denom = bit ? fabs(n1) : fabs(denom - n1);
            #pragma unroll
            for (int i = 0; i < PPT; ++i) {        // g-update from stashed regs
                gm[i] *= bit ? pym[i] : pxm[i];
                gk[i] *= bit ? pyk[i] : pxk[i];
            }
            if (tid == 0) out[n * L_ + l] = (float)bit;  // fire-and-forget
        }
    }

    if (tid == 0) out[N_ * L_ + n] = (float)(denom / initd);  // P_m carried for free
}

extern "C" void kernel_launch(void* const* d_in, const int* in_sizes, int n_in,
                              void* d_out, int out_size, void* d_ws, size_t ws_size,
                              hipStream_t stream) {
    const float* inp    = (const float*)d_in[0];   // (N,L)
    const float* theta  = (const float*)d_in[1];   // (L,M)
    const float* coef   = (const float*)d_in[2];   // (M,)
    const float* rand_u = (const float*)d_in[3];   // (L,N)
    float* out = (float*)d_out;                    // N*L bits then N probs
    mps_sample_kernel<<<N_, THREADS, 0, stream>>>(inp, theta, coef, rand_u, out);
}

// Round 4
// 96.822 us; speedup vs baseline: 2.1424x; 1.1643x over previous
//
#include <hip/hip_runtime.h>
#include <math.h>

#define M_ 48
#define L_ 48
#define N_ 256
#define THREADS 256
#define NPAIR_UT 1176          // upper triangle incl. diagonal
#define PPT 5                  // pairs per thread (strided), tail slots weight 0

// One block per sample. Per-pair combined prefix G[p]=gm*gk; suffix site
// matrices are fixed: register checkpoints every 8 sites (ckpt[5][PPT]) +
// per-segment register expansion R[8][PPT]; 2-step speculative evaluation
// -> ONE barrier per TWO measurements (24 total). Division-free decisions.
// LDS kept at ~37 KB (64 KB/workgroup limit killed R3's LDS checkpoints).
__launch_bounds__(THREADS, 1)
__global__ void mps_sample_kernel(const float* __restrict__ inp,
                                  const float* __restrict__ theta,
                                  const float* __restrict__ coef,
                                  const float* __restrict__ rand_u,
                                  float* __restrict__ out)
{
    const int n   = blockIdx.x;
    const int tid = threadIdx.x;

    __shared__ double s_pxy[L_][M_][2];    // (px,py) interleaved, b128-readable
    __shared__ double s_part[2][4][4];     // cross-wave partials, parity dbuf
    __shared__ float  s_u[L_];

    const double PI_2 = 1.5707963267948966;

    // ---- trig init: pxy[l][m] = coef[m] * (cos, sin)(theta + inp*(m+1)*pi/2) ----
    #pragma unroll
    for (int i = 0; i < 9; ++i) {
        int j = tid + THREADS * i;
        int l = j / M_, m = j - l * M_;
        double a  = (double)inp[n * L_ + l] * ((double)(m + 1) * PI_2);
        double th = (double)theta[l * M_ + m];
        double sv, cv; sincos(th + a, &sv, &cv);
        double cf = (double)coef[m];
        s_pxy[l][m][0] = cf * cv;
        s_pxy[l][m][1] = cf * sv;
    }
    if (tid < L_) s_u[tid] = rand_u[tid * N_ + n];

    // ---- strided upper-triangle pair decode ----
    int pm[PPT], pk[PPT];
    double wgt[PPT];
    #pragma unroll
    for (int i = 0; i < PPT; ++i) {
        int p = tid + THREADS * i;
        if (p < NPAIR_UT) {
            int m = 0, r = p;
            while (r >= M_ - m) { r -= M_ - m; ++m; }
            pm[i] = m; pk[i] = m + r;
            wgt[i] = (r == 0) ? 1.0 : 2.0;
        } else { pm[i] = 0; pk[i] = 0; wgt[i] = 0.0; }
    }
    __syncthreads();

    // ---- register checkpoints: ckpt[s] = w * prod_{l'>=8(s+1)} T_l' ----
    double ckpt[5][PPT];
    {
        double C[PPT];
        #pragma unroll
        for (int i = 0; i < PPT; ++i) C[i] = wgt[i];
        #pragma unroll
        for (int s = 4; s >= 0; --s) {
            #pragma unroll
            for (int lp = 7; lp >= 0; --lp) {
                int l = 8 * (s + 1) + lp;              // 47 .. 8
                #pragma unroll
                for (int i = 0; i < PPT; ++i) {
                    double2 vm = *(const double2*)&s_pxy[l][pm[i]][0];
                    double2 vk = *(const double2*)&s_pxy[l][pk[i]][0];
                    C[i] *= vm.x * vk.x + vm.y * vk.y;
                }
            }
            #pragma unroll
            for (int i = 0; i < PPT; ++i) ckpt[s][i] = C[i];
        }
    }

    double G[PPT];
    #pragma unroll
    for (int i = 0; i < PPT; ++i) G[i] = 1.0;

    double denom = 0.0, initd = 1.0;
    float  myBit = 0.0f;

    #pragma unroll
    for (int seg = 0; seg < 6; ++seg) {
        // ---- register expansion R[j] = w * S_{8seg+j+1} ----
        double R[8][PPT], Crun[PPT];
        #pragma unroll
        for (int i = 0; i < PPT; ++i)
            Crun[i] = (seg == 5) ? wgt[i] : ckpt[seg == 5 ? 0 : seg][i];
        #pragma unroll
        for (int j = 7; j >= 0; --j) {
            #pragma unroll
            for (int i = 0; i < PPT; ++i) R[j][i] = Crun[i];
            if (j > 0) {
                int l2 = 8 * seg + j;
                #pragma unroll
                for (int i = 0; i < PPT; ++i) {
                    double2 vm = *(const double2*)&s_pxy[l2][pm[i]][0];
                    double2 vk = *(const double2*)&s_pxy[l2][pk[i]][0];
                    Crun[i] *= vm.x * vk.x + vm.y * vk.y;
                }
            }
        }

        // ---- 4 iterations x 2 speculative steps ----
        #pragma unroll
        for (int half = 0; half < 4; ++half) {
            const int ls  = 2 * half;
            const int l   = 8 * seg + ls;
            const int par = half & 1;
            double X0[PPT], Y0[PPT], X1[PPT], Y1[PPT];
            double n1L = 0.0, h0 = 0.0, h1 = 0.0, nT = 0.0;
            #pragma unroll
            for (int i = 0; i < PPT; ++i) {
                double2 vm0 = *(const double2*)&s_pxy[l][pm[i]][0];
                double2 vk0 = *(const double2*)&s_pxy[l][pk[i]][0];
                double2 vm1 = *(const double2*)&s_pxy[l + 1][pm[i]][0];
                double2 vk1 = *(const double2*)&s_pxy[l + 1][pk[i]][0];
                X0[i] = vm0.x * vk0.x;  Y0[i] = vm0.y * vk0.y;
                X1[i] = vm1.x * vk1.x;  Y1[i] = vm1.y * vk1.y;
                double t0 = G[i] * R[ls][i];
                double t1 = G[i] * R[ls + 1][i];
                n1L = fma(t0, Y0[i], n1L);
                if (seg == 0 && half == 0) nT = fma(t0, X0[i], nT); // denom seed
                h0 = fma(t1 * X0[i], Y1[i], h0);          // hypothesis bit_l = 0
                h1 = fma(t1 * Y0[i], Y1[i], h1);          // hypothesis bit_l = 1
            }
            // butterfly: every lane ends with the identical full wave sum
            #pragma unroll
            for (int off = 1; off < 64; off <<= 1) {
                n1L += __shfl_xor(n1L, off, 64);
                h0  += __shfl_xor(h0,  off, 64);
                h1  += __shfl_xor(h1,  off, 64);
                if (seg == 0 && half == 0) nT += __shfl_xor(nT, off, 64);
            }
            const int wv = tid >> 6;
            if ((tid & 63) == 0) {
                s_part[par][wv][0] = n1L; s_part[par][wv][1] = h0;
                s_part[par][wv][2] = h1;  s_part[par][wv][3] = nT;
            }
            __syncthreads();
            double sn1 = s_part[par][0][0] + s_part[par][1][0] + s_part[par][2][0] + s_part[par][3][0];
            double sh0 = s_part[par][0][1] + s_part[par][1][1] + s_part[par][2][1] + s_part[par][3][1];
            double sh1 = s_part[par][0][2] + s_part[par][1][2] + s_part[par][2][2] + s_part[par][3][2];
            if (seg == 0 && half == 0) {
                double snT = s_part[par][0][3] + s_part[par][1][3] + s_part[par][2][3] + s_part[par][3][3];
                denom = fabs(snT + sn1);
                initd = denom;
            }
            // two bit decisions, division-free (denom = <psi|psi> > 0)
            double a1  = fabs(sn1);
            int bitA   = ((double)s_u[l] * denom < a1) ? 1 : 0;
            denom      = bitA ? a1 : fabs(denom - sn1);
            double n1b = bitA ? sh1 : sh0;
            double a2  = fabs(n1b);
            int bitB   = ((double)s_u[l + 1] * denom < a2) ? 1 : 0;
            denom      = bitB ? a2 : fabs(denom - n1b);
            // fused two-step prefix update
            #pragma unroll
            for (int i = 0; i < PPT; ++i) {
                double c0 = bitA ? Y0[i] : X0[i];
                double c1 = bitB ? Y1[i] : X1[i];
                G[i] *= c0 * c1;
            }
            if (tid == l)     myBit = (float)bitA;
            if (tid == l + 1) myBit = (float)bitB;
        }
    }

    if (tid < L_)  out[n * L_ + tid] = myBit;                 // bits, one burst
    if (tid == 0)  out[N_ * L_ + n] = (float)(denom / initd); // P_m carried free
}

extern "C" void kernel_launch(void* const* d_in, const int* in_sizes, int n_in,
                              void* d_out, int out_size, void* d_ws, size_t ws_size,
                              hipStream_t stream) {
    const float* inp    = (const float*)d_in[0];   // (N,L)
    const float* theta  = (const float*)d_in[1];   // (L,M)
    const float* coef   = (const float*)d_in[2];   // (M,)
    const float* rand_u = (const float*)d_in[3];   // (L,N)
    float* out = (float*)d_out;                    // N*L bits then N probs
    mps_sample_kernel<<<N_, THREADS, 0, stream>>>(inp, theta, coef, rand_u, out);
}